// Round 15
// baseline (113.583 us; speedup 1.0000x reference)
//
#include <hip/hip_runtime.h>
#include <math.h>

#define B_ 2
#define L_ 2048
#define HID_ 1024
#define NH_ 16
#define HD_ 64
#define QBLK 128

typedef unsigned short u16;
typedef __attribute__((ext_vector_type(8))) _Float16 half8;  // 8 fp16 = 4 VGPR
typedef __attribute__((ext_vector_type(4))) float f32x4;
typedef __attribute__((ext_vector_type(16))) float f32x16;

__device__ __forceinline__ u16 f2h(float x) { // RNE fp32 -> fp16 bits
    _Float16 h = (_Float16)x; u16 r; __builtin_memcpy(&r, &h, 2); return r;
}
__device__ __forceinline__ float fexp2(float x) { // v_exp_f32, 1 inst
    float r;
    asm("v_exp_f32 %0, %1" : "=v"(r) : "v"(x));
    return r;
}
__device__ __forceinline__ unsigned pkrtz(float a, float b) { // 2xf32 -> packed fp16x2
    auto v = __builtin_amdgcn_cvt_pkrtz(a, b); // __fp16 ext_vector(2)
    unsigned r; __builtin_memcpy(&r, &v, 4); return r;
}
__device__ __forceinline__ void gload16(const void* g, void* l) {
    __builtin_amdgcn_global_load_lds(
        (const __attribute__((address_space(1))) void*)g,
        (__attribute__((address_space(3))) void*)l, 16, 0, 0);
}

// ---------------------------------------------------------------------------
// Kernel 1: per-batch segment bookkeeping
// ---------------------------------------------------------------------------
__global__ void setup_kernel(const int* __restrict__ aml,
                             int* __restrict__ sstart, int* __restrict__ send,
                             int* __restrict__ poss_out)
{
    const int b = blockIdx.x;
    const int tid = threadIdx.x;
    __shared__ int cs[L_];
    __shared__ int partial[256];

    int vals[8];
    const int t0 = tid * 8;
    int s = 0;
#pragma unroll
    for (int e = 0; e < 8; ++e) { vals[e] = aml[b * L_ + t0 + e]; s += vals[e]; }
    partial[tid] = s;
    __syncthreads();
    if (tid == 0) {
        int acc = 0;
        for (int i = 0; i < 256; ++i) { int tmp = partial[i]; partial[i] = acc; acc += tmp; }
    }
    __syncthreads();
    int off = partial[tid];
#pragma unroll
    for (int e = 0; e < 8; ++e) { off += vals[e]; cs[t0 + e] = off; }
    __syncthreads();

    const int total = cs[L_ - 1];
    for (int t = tid; t < L_; t += 256) {
        int lo = 0, hi = L_;
        while (lo < hi) { int mid = (lo + hi) >> 1; if (cs[mid] <= t) lo = mid + 1; else hi = mid; }
        int seg = lo < (L_ - 1) ? lo : (L_ - 1);
        int end = cs[seg];
        int len = aml[b * L_ + seg];
        int start = end - len;
        bool valid = t < total;
        poss_out[b * L_ + t] = valid ? (t - start) : 0;
        sstart[b * L_ + t] = valid ? start : 0x7fffffff;
        send[b * L_ + t]   = valid ? end : 0;
    }
}

// ---------------------------------------------------------------------------
// Kernel 2: merged conversions + trig (one launch)
// ---------------------------------------------------------------------------
__global__ void conv_all(const float* __restrict__ hidden, u16* __restrict__ hidh,
                         const float* __restrict__ Wqkv, u16* __restrict__ wqh,
                         const float* __restrict__ Wout, u16* __restrict__ woh,
                         const int* __restrict__ poss,
                         float* __restrict__ ctab, float* __restrict__ stab)
{
    __shared__ float t[32][33];
    const int bid = blockIdx.x;
    const int tid = threadIdx.x;
    if (bid < 4096) {
        int i = (bid * 256 + tid) * 4;
        float4 v = *(const float4*)&hidden[i];
        *(ushort4*)&hidh[i] = make_ushort4(f2h(v.x), f2h(v.y), f2h(v.z), f2h(v.w));
        return;
    }
    if (bid >= 8192) {
        const double kexp = 13.287712379549449 / 32.0; // log2(10000)/32
        int idx = (bid - 8192) * 256 + tid;            // (b*L + t)*32 + d
        int d = idx & 31;
        int bt = idx >> 5;
        double f = (double)poss[bt] * exp2(-(double)d * kexp);
        ctab[idx] = (float)cos(f);
        stab[idx] = (float)sin(f);
        return;
    }
    const float* W; u16* o; int Kd = 1024, Nd, n0, k0;
    if (bid < 7168) {
        int idx = bid - 4096; W = Wqkv; o = wqh; Nd = 3072;
        n0 = (idx % 96) * 32; k0 = (idx / 96) * 32;
    } else {
        int idx = bid - 7168; W = Wout; o = woh; Nd = 1024;
        n0 = (idx & 31) * 32; k0 = (idx >> 5) * 32;
    }
    const int r = tid >> 5, c = tid & 31;
#pragma unroll
    for (int i = 0; i < 4; ++i)
        t[r + 8 * i][c] = W[(size_t)(k0 + r + 8 * i) * Nd + n0 + c];
    __syncthreads();
#pragma unroll
    for (int i = 0; i < 4; ++i)
        o[(size_t)(n0 + r + 8 * i) * Kd + k0 + c] = f2h(t[c][r + 8 * i]);
}

// ---------------------------------------------------------------------------
// Kernel 3/5: single-plane fp16 MFMA GEMM (m97 structure, verified).
// MODE 0: C fp32 row-major + bias.
// MODE 1: fused RoPE on q,k -> fp16 [B,NH,L,HD]; v -> fp16 transposed
//         vt [B,NH,HD,L].
// ---------------------------------------------------------------------------
template <int MODE>
__global__ __launch_bounds__(256, 3)
void gemm_mfma(const u16* __restrict__ Ap, const u16* __restrict__ Bp,
               const float* __restrict__ bias, float* __restrict__ C,
               u16* __restrict__ qb, u16* __restrict__ kb, u16* __restrict__ vtb,
               const float* __restrict__ ctab, const float* __restrict__ stab,
               int M, int N, int K)
{
    __shared__ u16 Asl[128 * 64]; // A tile
    __shared__ u16 Bsl[128 * 64]; // B tile

    const int tid = threadIdx.x;
    const int wave = tid >> 6, lane = tid & 63;

    const int nwg = gridDim.x * gridDim.y;
    const int bid = blockIdx.y * gridDim.x + blockIdx.x;
    const int cpx = nwg >> 3;
    const int swz = (bid & 7) * cpx + (bid >> 3);
    const int brow = (swz / gridDim.x) * 128;
    const int bcol = (swz % gridDim.x) * 128;

    const int wr = (wave >> 1) * 64, wc = (wave & 1) * 64;
    const int grow = tid >> 3, gslot = tid & 7;
    const int fr = lane & 15, kg = lane >> 4;

    f32x4 acc[4][4];
#pragma unroll
    for (int m = 0; m < 4; ++m)
#pragma unroll
        for (int n = 0; n < 4; ++n) acc[m][n] = (f32x4){0.f, 0.f, 0.f, 0.f};

    for (int ka = 0; ka < K; ka += 64) {
#pragma unroll
        for (int c = 0; c < 4; ++c) {
            int row = c * 32 + grow;
            int sg = gslot ^ (row & 7);
            gload16(&Ap[(size_t)(brow + row) * K + ka + sg * 8],
                    (char*)Asl + c * 4096 + wave * 1024);
            gload16(&Bp[(size_t)(bcol + row) * K + ka + sg * 8],
                    (char*)Bsl + c * 4096 + wave * 1024);
        }
        __syncthreads();

#pragma unroll
        for (int kk = 0; kk < 2; ++kk) {
            half8 af[4], bfv[4];
            const int cbase = kk * 4 + kg;
#pragma unroll
            for (int n = 0; n < 4; ++n) {
                int r = wc + n * 16 + fr;
                bfv[n] = *(const half8*)&Bsl[r * 64 + ((cbase ^ (r & 7)) << 3)];
            }
#pragma unroll
            for (int m = 0; m < 4; ++m) {
                int r = wr + m * 16 + fr;
                af[m] = *(const half8*)&Asl[r * 64 + ((cbase ^ (r & 7)) << 3)];
            }
#pragma unroll
            for (int m = 0; m < 4; ++m)
#pragma unroll
                for (int n = 0; n < 4; ++n)
                    acc[m][n] = __builtin_amdgcn_mfma_f32_16x16x32_f16(
                        af[m], bfv[n], acc[m][n], 0, 0, 0);
        }
        __syncthreads();
    }

    // epilogue: C/D layout col = lane&15, row = (lane>>4)*4 + reg
    const int cr = (lane >> 4) * 4;
    const int cc = lane & 15;
    if (MODE == 0) {
#pragma unroll
        for (int m = 0; m < 4; ++m) {
#pragma unroll
            for (int n = 0; n < 4; ++n) {
                const int col = bcol + wc + n * 16 + cc;
                const float bv = bias[col];
                const int row0 = brow + wr + m * 16 + cr;
#pragma unroll
                for (int rg = 0; rg < 4; ++rg)
                    C[(size_t)(row0 + rg) * N + col] = acc[m][n][rg] + bv;
            }
        }
    } else {
        const int colbase = bcol + wc;            // 64-aligned: one (matrix, head)
        const int sel = colbase >> 10;            // 0=q 1=k 2=v
        const int hh = (colbase & 1023) >> 6;
#pragma unroll
        for (int m = 0; m < 4; ++m) {
            const int row0 = brow + wr + m * 16 + cr;
            const int bidx = row0 >> 11, t0 = row0 & (L_ - 1);
            if (sel == 2) { // v -> transposed fp16
#pragma unroll
                for (int n = 0; n < 4; ++n) {
                    int col = colbase + n * 16 + cc;
                    float bv = bias[col];
                    int d = col & 63;
                    ushort4 pk = make_ushort4(
                        f2h(acc[m][n][0] + bv), f2h(acc[m][n][1] + bv),
                        f2h(acc[m][n][2] + bv), f2h(acc[m][n][3] + bv));
                    *(ushort4*)&vtb[((((size_t)bidx * NH_ + hh) * HD_) + d) * L_ + t0] = pk;
                }
            } else {        // q or k -> fused RoPE, fp16
                u16* dst = (sel == 0) ? qb : kb;
#pragma unroll
                for (int np = 0; np < 2; ++np) {
                    int col1 = colbase + np * 16 + cc;
                    int d1 = np * 16 + cc;        // [0,32)
                    float bv1 = bias[col1], bv2 = bias[col1 + 32];
#pragma unroll
                    for (int rg = 0; rg < 4; ++rg) {
                        int t = t0 + rg;
                        float c = ctab[((size_t)bidx * L_ + t) * 32 + d1];
                        float s = stab[((size_t)bidx * L_ + t) * 32 + d1];
                        float x1 = acc[m][np][rg] + bv1;
                        float x2 = acc[m][np + 2][rg] + bv2;
                        size_t base = ((((size_t)bidx * NH_ + hh) * L_) + t) * (size_t)HD_;
                        dst[base + d1]      = f2h(x1 * c - x2 * s);
                        dst[base + d1 + 32] = f2h(x2 * c + x1 * s);
                    }
                }
            }
        }
    }
}

// ---------------------------------------------------------------------------
// Kernel 4: segment-masked flash attention on 32x32x16 MFMA.
// 4 waves x 32 q-rows (QBLK=128).  Swapped operands throughout:
//   S^T = mfma(K_frag, Q_frag): D[row=key][col=q]; per wave: 2 key-halves
//   x 4 d-slices = 8 MFMA.  Lane (q=lane&31, hi=lane>>5) holds 32 score
//   regs covering ALL 64 keys of the tile (keys of one q split lane/lane+32
//   -> softmax = 31 local adds + 1 shfl_xor(32)).
// P->B-fragment conversion IN REGISTER (no LDS): 16 pkrtz + 16 shfl_xor(32)
//   + cndmask assembly (C row formula (r&3)+8*(r>>2)+4*hi drives the map).
// PV: O^T = mfma(Vt_frag, P_frag): D[row=d][col=q]; 2 d-tiles x 4 key-slices.
// LDS: double-buffered K/V only (32 KB), r11-style simple dbuf loop.
// C/D 32x32 layout: col=lane&31, row=(reg&3)+8*(reg>>2)+4*(lane>>5) [m74/m101].
// ---------------------------------------------------------------------------
__global__ __launch_bounds__(256)
void attn_mfma(const u16* __restrict__ qb, const u16* __restrict__ kbuf,
               const u16* __restrict__ vt, const int* __restrict__ sstart,
               const int* __restrict__ send, u16* __restrict__ ohi)
{
    __shared__ u16 Ksb[2][64 * 64];
    __shared__ u16 Vsb[2][64 * 64];
    __shared__ int ss[QBLK], se[QBLK];

    const int b = blockIdx.z, h = blockIdx.y, q0 = blockIdx.x * QBLK;
    const int tid = threadIdx.x, wave = tid >> 6, lane = tid & 63;
    const int l31 = lane & 31, hi = lane >> 5;
    const size_t hb = (((size_t)b * NH_) + h) * (size_t)(L_ * HD_); // qb,kb
    const size_t hv = (((size_t)b * NH_) + h) * (size_t)(HD_ * L_); // vt

    if (tid < QBLK) { ss[tid] = sstart[b * L_ + q0 + tid]; se[tid] = send[b * L_ + q0 + tid]; }

    // Q B-fragments: q = q0 + wave*32 + l31; slice s: d = s*16 + hi*8 + j
    const u16* qptr = &qb[hb + (size_t)(q0 + wave * 32 + l31) * HD_ + hi * 8];
    half8 qf[4];
#pragma unroll
    for (int s = 0; s < 4; ++s) qf[s] = *(const half8*)(qptr + s * 16);
    __syncthreads();

    int kmin = 0x7fffffff, kmax = 0;
#pragma unroll 8
    for (int r = 0; r < QBLK; ++r) { kmin = min(kmin, ss[r]); kmax = max(kmax, se[r]); }

    const int myss_ = ss[wave * 32 + l31];  // per-lane: one q-row
    const int myse_ = se[wave * 32 + l31];

    float l_ = 0.f;
    f32x16 oacc[2];
#pragma unroll
    for (int i = 0; i < 16; ++i) { oacc[0][i] = 0.f; oacc[1][i] = 0.f; }

    // staging: 256 threads x 16B x 2 rounds = one 64x64 fp16 tile
    const int grow = tid >> 3;              // rows 0..31 (round c adds c*32)
    const int sg = (tid & 7) ^ (grow & 7);  // (c*32+grow)&7 == grow&7
    const float SCL = 0.015625f * 1.4426950408889634f; // (1/64)*log2(e)
    const int fx = l31 & 7;

    const int kt_first = kmin & ~63;
    const int ntile = (kmax > kt_first) ? ((kmax - kt_first + 63) >> 6) : 0;

    if (ntile > 0) {
#pragma unroll
        for (int c = 0; c < 2; ++c) {
            int row = c * 32 + grow;
            gload16(&kbuf[hb + (size_t)(kt_first + row) * HD_ + sg * 8],
                    (char*)Ksb[0] + c * 4096 + wave * 1024);
            gload16(&vt[hv + (size_t)row * L_ + kt_first + sg * 8],
                    (char*)Vsb[0] + c * 4096 + wave * 1024);
        }
    }
    __syncthreads();

    int bufi = 0;
    for (int i = 0; i < ntile; ++i) {
        const int kt0 = kt_first + i * 64;
        // prefetch next tile into the other buffer
        if (i + 1 < ntile) {
            const int ktn = kt0 + 64;
#pragma unroll
            for (int c = 0; c < 2; ++c) {
                int row = c * 32 + grow;
                gload16(&kbuf[hb + (size_t)(ktn + row) * HD_ + sg * 8],
                        (char*)Ksb[bufi ^ 1] + c * 4096 + wave * 1024);
                gload16(&vt[hv + (size_t)row * L_ + ktn + sg * 8],
                        (char*)Vsb[bufi ^ 1] + c * 4096 + wave * 1024);
            }
        }
        const u16* Ks = Ksb[bufi];
        const u16* Vs = Vsb[bufi];

        // ---- QK^T swapped: sc0/sc1 = S^T for key-halves 0/1 (32 keys each)
        f32x16 sc0, sc1;
#pragma unroll
        for (int r = 0; r < 16; ++r) { sc0[r] = 0.f; sc1[r] = 0.f; }
        __builtin_amdgcn_s_setprio(1);
#pragma unroll
        for (int s = 0; s < 4; ++s) {
            const int sl = (((s << 1) + hi) ^ fx) << 3; // swizzled 8-u16 slot
            half8 a0 = *(const half8*)&Ks[l31 * 64 + sl];
            half8 a1 = *(const half8*)&Ks[(32 + l31) * 64 + sl];
            sc0 = __builtin_amdgcn_mfma_f32_32x32x16_f16(a0, qf[s], sc0, 0, 0, 0);
            sc1 = __builtin_amdgcn_mfma_f32_32x32x16_f16(a1, qf[s], sc1, 0, 0, 0);
        }
        __builtin_amdgcn_s_setprio(0);

        // ---- softmax (no max-subtraction; scores tiny, shift-invariant)
        float psum = 0.f;
        if (__all((kt0 >= myss_) && (kt0 + 64 <= myse_))) {
#pragma unroll
            for (int r = 0; r < 16; ++r) {
                sc0[r] = fexp2(sc0[r] * SCL); psum += sc0[r];
                sc1[r] = fexp2(sc1[r] * SCL); psum += sc1[r];
            }
        } else {
            const int ktb = kt0 + 4 * hi;
#pragma unroll
            for (int r = 0; r < 16; ++r) {
                int key0 = ktb + (r & 3) + 8 * (r >> 2);
                int key1 = key0 + 32;
                bool v0 = (key0 >= myss_) && (key0 < myse_);
                bool v1 = (key1 >= myss_) && (key1 < myse_);
                float e0 = fexp2(sc0[r] * SCL);
                float e1 = fexp2(sc1[r] * SCL);
                sc0[r] = v0 ? e0 : 0.f; psum += sc0[r];
                sc1[r] = v1 ? e1 : 0.f; psum += sc1[r];
            }
        }
        psum += __shfl_xor(psum, 32);
        l_ += psum;

        // ---- pack P to fp16 pairs; exchange lane<->lane+32 in register
        // w[kh][g] covers keys kh*32 + 8g + 4hi + {0..3} (packed 2x u32)
        unsigned w0[4][2], w1[4][2], p0[4][2], p1[4][2];
#pragma unroll
        for (int g = 0; g < 4; ++g) {
            w0[g][0] = pkrtz(sc0[4 * g + 0], sc0[4 * g + 1]);
            w0[g][1] = pkrtz(sc0[4 * g + 2], sc0[4 * g + 3]);
            w1[g][0] = pkrtz(sc1[4 * g + 0], sc1[4 * g + 1]);
            w1[g][1] = pkrtz(sc1[4 * g + 2], sc1[4 * g + 3]);
            p0[g][0] = __shfl_xor(w0[g][0], 32);
            p0[g][1] = __shfl_xor(w0[g][1], 32);
            p1[g][0] = __shfl_xor(w1[g][0], 32);
            p1[g][1] = __shfl_xor(w1[g][1], 32);
        }

        // ---- PV swapped: oacc[dt] += mfma(Vt_frag, P_frag) -> O^T[d][q]
        __builtin_amdgcn_s_setprio(1);
#pragma unroll
        for (int s = 0; s < 4; ++s) {       // 16-key slice: keys s*16..+15
            const int s1 = s & 1;
            // B-frag: P[key = s*16 + hi*8 + j][q = l31]
            unsigned bw[4];
            if ((s >> 1) == 0) {
                bw[0] = hi ? p0[2 * s1 + 1][0] : w0[2 * s1][0];
                bw[1] = hi ? p0[2 * s1 + 1][1] : w0[2 * s1][1];
                bw[2] = hi ? w0[2 * s1 + 1][0] : p0[2 * s1][0];
                bw[3] = hi ? w0[2 * s1 + 1][1] : p0[2 * s1][1];
            } else {
                bw[0] = hi ? p1[2 * s1 + 1][0] : w1[2 * s1][0];
                bw[1] = hi ? p1[2 * s1 + 1][1] : w1[2 * s1][1];
                bw[2] = hi ? w1[2 * s1 + 1][0] : p1[2 * s1][0];
                bw[3] = hi ? w1[2 * s1 + 1][1] : p1[2 * s1][1];
            }
            half8 pf; __builtin_memcpy(&pf, bw, 16);
            const int sl = (((s << 1) + hi) ^ fx) << 3;
#pragma unroll
            for (int dt = 0; dt < 2; ++dt) {
                half8 vf = *(const half8*)&Vs[(dt * 32 + l31) * 64 + sl];
                oacc[dt] = __builtin_amdgcn_mfma_f32_32x32x16_f16(vf, pf, oacc[dt], 0, 0, 0);
            }
        }
        __builtin_amdgcn_s_setprio(0);
        __syncthreads(); // prefetch landed + all waves done with bufi
        bufi ^= 1;
    }

    // ---- epilogue: q = q0+wave*32+l31; d = dt*32 + 8g + 4hi + {0..3}
    const int t = q0 + wave * 32 + l31;
    const float inv = (myss_ < myse_) ? 1.f / l_ : 0.f;
    const size_t rowbase = ((size_t)b * L_ + t) * (size_t)HID_ + h * HD_;
#pragma unroll
    for (int dt = 0; dt < 2; ++dt)
#pragma unroll
        for (int g = 0; g < 4; ++g) {
            ushort4 o = make_ushort4(
                f2h(oacc[dt][4 * g + 0] * inv), f2h(oacc[dt][4 * g + 1] * inv),
                f2h(oacc[dt][4 * g + 2] * inv), f2h(oacc[dt][4 * g + 3] * inv));
            *(ushort4*)&ohi[rowbase + dt * 32 + 8 * g + 4 * hi] = o;
        }
}

// ---------------------------------------------------------------------------
extern "C" void kernel_launch(void* const* d_in, const int* in_sizes, int n_in,
                              void* d_out, int out_size, void* d_ws, size_t ws_size,
                              hipStream_t stream)
{
    (void)in_sizes; (void)n_in; (void)out_size; (void)ws_size;
    const float* hidden = (const float*)d_in[0];
    const int*   aml    = (const int*)d_in[1];
    const float* Wqkv   = (const float*)d_in[2];
    const float* bqkv   = (const float*)d_in[3];
    const float* Wout   = (const float*)d_in[4];
    const float* bout   = (const float*)d_in[5];
    float* out = (float*)d_out;

    const size_t per = (size_t)B_ * NH_ * L_ * HD_; // 4,194,304
    float* ctab = (float*)d_ws;
    float* stab = ctab + (size_t)B_ * L_ * 32;
    int* sstart = (int*)(stab + (size_t)B_ * L_ * 32);
    int* send   = sstart + B_ * L_;
    int* poss   = send + B_ * L_;
    u16* qbf  = (u16*)(poss + B_ * L_);             // fp16 q (post-rope)
    u16* kbf  = qbf + per;                          // fp16 k (post-rope)
    u16* vtb  = kbf + per;                          // fp16 v transposed [B,NH,HD,L]
    u16* hidh = vtb + per;                          // fp16 A plane (hidden, then attn-out)
    u16* wqh  = hidh + (size_t)4096 * 1024;         // WqkvT fp16 [3072][1024]
    u16* woh  = wqh + (size_t)3072 * 1024;          // WoutT fp16 [1024][1024]

    setup_kernel<<<dim3(B_), dim3(256), 0, stream>>>(aml, sstart, send, poss);

    conv_all<<<dim3(8704), dim3(256), 0, stream>>>(hidden, hidh, Wqkv, wqh,
                                                   Wout, woh, poss, ctab, stab);

    gemm_mfma<1><<<dim3(24, 32), dim3(256), 0, stream>>>(
        hidh, wqh, bqkv, nullptr, qbf, kbf, vtb, ctab, stab,
        B_ * L_, 3 * HID_, HID_);

    attn_mfma<<<dim3(L_ / QBLK, NH_, B_), dim3(256), 0, stream>>>(
        qbf, kbf, vtb, sstart, send, hidh);

    gemm_mfma<0><<<dim3(8, 32), dim3(256), 0, stream>>>(
        hidh, woh, bout, out, nullptr, nullptr, nullptr, nullptr, nullptr,
        B_ * L_, HID_, HID_);
}

// Round 16
// 105.850 us; speedup vs baseline: 1.0731x; 1.0731x over previous
//
#include <hip/hip_runtime.h>
#include <math.h>

#define B_ 2
#define L_ 2048
#define HID_ 1024
#define NH_ 16
#define HD_ 64
#define QBLK 128

typedef unsigned short u16;
typedef __attribute__((ext_vector_type(8))) _Float16 half8; // 8 fp16 = 4 VGPR
typedef __attribute__((ext_vector_type(4))) float f32x4;

__device__ __forceinline__ u16 f2h(float x) { // RNE fp32 -> fp16 bits
    _Float16 h = (_Float16)x; u16 r; __builtin_memcpy(&r, &h, 2); return r;
}
__device__ __forceinline__ float fexp2(float x) { // v_exp_f32, 1 inst
    float r;
    asm("v_exp_f32 %0, %1" : "=v"(r) : "v"(x));
    return r;
}
__device__ __forceinline__ unsigned pkrtz(float a, float b) { // 2xf32 -> packed fp16x2
    auto v = __builtin_amdgcn_cvt_pkrtz(a, b); // __fp16 ext_vector(2)
    unsigned r; __builtin_memcpy(&r, &v, 4); return r;
}
__device__ __forceinline__ void gload16(const void* g, void* l) {
    __builtin_amdgcn_global_load_lds(
        (const __attribute__((address_space(1))) void*)g,
        (__attribute__((address_space(3))) void*)l, 16, 0, 0);
}

// ---------------------------------------------------------------------------
// Kernel 1: merged conversions + segment bookkeeping (one launch):
//  blocks [0,4096)        : hidden fp32 -> fp16 plane (row-linear)
//  blocks [4096,7168)     : Wqkv  [1024][3072] -> WqkvT fp16 [3072][1024]
//  blocks [7168,8192)     : Wout  [1024][1024] -> WoutT fp16 [1024][1024]
//  blocks [8192,8194)     : per-batch segment bookkeeping (prefix sum etc.)
// ---------------------------------------------------------------------------
__global__ void conv_all(const float* __restrict__ hidden, u16* __restrict__ hidh,
                         const float* __restrict__ Wqkv, u16* __restrict__ wqh,
                         const float* __restrict__ Wout, u16* __restrict__ woh,
                         const int* __restrict__ aml,
                         int* __restrict__ sstart, int* __restrict__ send,
                         int* __restrict__ poss_out)
{
    __shared__ float t[32][33];
    const int bid = blockIdx.x;
    const int tid = threadIdx.x;
    if (bid < 4096) {
        int i = (bid * 256 + tid) * 4;
        float4 v = *(const float4*)&hidden[i];
        *(ushort4*)&hidh[i] = make_ushort4(f2h(v.x), f2h(v.y), f2h(v.z), f2h(v.w));
        return;
    }
    if (bid >= 8192) { // segment bookkeeping, b = bid - 8192
        const int b = bid - 8192;
        __shared__ int cs[L_];
        __shared__ int partial[256];
        int vals[8];
        const int t0 = tid * 8;
        int s = 0;
#pragma unroll
        for (int e = 0; e < 8; ++e) { vals[e] = aml[b * L_ + t0 + e]; s += vals[e]; }
        partial[tid] = s;
        __syncthreads();
        if (tid == 0) {
            int acc = 0;
            for (int i = 0; i < 256; ++i) { int tmp = partial[i]; partial[i] = acc; acc += tmp; }
        }
        __syncthreads();
        int off = partial[tid];
#pragma unroll
        for (int e = 0; e < 8; ++e) { off += vals[e]; cs[t0 + e] = off; }
        __syncthreads();
        const int total = cs[L_ - 1];
        for (int tt = tid; tt < L_; tt += 256) {
            int lo = 0, hi = L_;
            while (lo < hi) { int mid = (lo + hi) >> 1; if (cs[mid] <= tt) lo = mid + 1; else hi = mid; }
            int seg = lo < (L_ - 1) ? lo : (L_ - 1);
            int end = cs[seg];
            int len = aml[b * L_ + seg];
            int start = end - len;
            bool valid = tt < total;
            poss_out[b * L_ + tt] = valid ? (tt - start) : 0;
            sstart[b * L_ + tt] = valid ? start : 0x7fffffff;
            send[b * L_ + tt]   = valid ? end : 0;
        }
        return;
    }
    const float* W; u16* o; int Kd = 1024, Nd, n0, k0;
    if (bid < 7168) {
        int idx = bid - 4096; W = Wqkv; o = wqh; Nd = 3072;
        n0 = (idx % 96) * 32; k0 = (idx / 96) * 32;
    } else {
        int idx = bid - 7168; W = Wout; o = woh; Nd = 1024;
        n0 = (idx & 31) * 32; k0 = (idx >> 5) * 32;
    }
    const int r = tid >> 5, c = tid & 31;
#pragma unroll
    for (int i = 0; i < 4; ++i)
        t[r + 8 * i][c] = W[(size_t)(k0 + r + 8 * i) * Nd + n0 + c];
    __syncthreads();
#pragma unroll
    for (int i = 0; i < 4; ++i)
        o[(size_t)(n0 + r + 8 * i) * Kd + k0 + c] = f2h(t[c][r + 8 * i]);
}

// ---------------------------------------------------------------------------
// Kernel 2: RoPE cos/sin tables, one entry per thread (needs poss)
// ---------------------------------------------------------------------------
__global__ void trig_kernel(const int* __restrict__ poss,
                            float* __restrict__ ctab, float* __restrict__ stab)
{
    const double kexp = 13.287712379549449 / 32.0; // log2(10000)/32
    int idx = blockIdx.x * 256 + threadIdx.x;      // (b*L + t)*32 + d
    int d = idx & 31;
    int bt = idx >> 5;
    double f = (double)poss[bt] * exp2(-(double)d * kexp);
    ctab[idx] = (float)cos(f);
    stab[idx] = (float)sin(f);
}

// ---------------------------------------------------------------------------
// Kernel 3/5: single-plane fp16 MFMA GEMM (m97 structure, verified).
// MODE 0: C fp32 row-major + bias.
// MODE 1: fused RoPE on q,k -> fp16 [B,NH,L,HD]; v -> fp16 transposed
//         vt [B,NH,HD,L].
// ---------------------------------------------------------------------------
template <int MODE>
__global__ __launch_bounds__(256, 3)
void gemm_mfma(const u16* __restrict__ Ap, const u16* __restrict__ Bp,
               const float* __restrict__ bias, float* __restrict__ C,
               u16* __restrict__ qb, u16* __restrict__ kb, u16* __restrict__ vtb,
               const float* __restrict__ ctab, const float* __restrict__ stab,
               int M, int N, int K)
{
    __shared__ u16 Asl[128 * 64]; // A tile
    __shared__ u16 Bsl[128 * 64]; // B tile

    const int tid = threadIdx.x;
    const int wave = tid >> 6, lane = tid & 63;

    const int nwg = gridDim.x * gridDim.y;
    const int bid = blockIdx.y * gridDim.x + blockIdx.x;
    const int cpx = nwg >> 3;
    const int swz = (bid & 7) * cpx + (bid >> 3);
    const int brow = (swz / gridDim.x) * 128;
    const int bcol = (swz % gridDim.x) * 128;

    const int wr = (wave >> 1) * 64, wc = (wave & 1) * 64;
    const int grow = tid >> 3, gslot = tid & 7;
    const int fr = lane & 15, kg = lane >> 4;

    f32x4 acc[4][4];
#pragma unroll
    for (int m = 0; m < 4; ++m)
#pragma unroll
        for (int n = 0; n < 4; ++n) acc[m][n] = (f32x4){0.f, 0.f, 0.f, 0.f};

    for (int ka = 0; ka < K; ka += 64) {
#pragma unroll
        for (int c = 0; c < 4; ++c) {
            int row = c * 32 + grow;
            int sg = gslot ^ (row & 7);
            gload16(&Ap[(size_t)(brow + row) * K + ka + sg * 8],
                    (char*)Asl + c * 4096 + wave * 1024);
            gload16(&Bp[(size_t)(bcol + row) * K + ka + sg * 8],
                    (char*)Bsl + c * 4096 + wave * 1024);
        }
        __syncthreads();

#pragma unroll
        for (int kk = 0; kk < 2; ++kk) {
            half8 af[4], bfv[4];
            const int cbase = kk * 4 + kg;
#pragma unroll
            for (int n = 0; n < 4; ++n) {
                int r = wc + n * 16 + fr;
                bfv[n] = *(const half8*)&Bsl[r * 64 + ((cbase ^ (r & 7)) << 3)];
            }
#pragma unroll
            for (int m = 0; m < 4; ++m) {
                int r = wr + m * 16 + fr;
                af[m] = *(const half8*)&Asl[r * 64 + ((cbase ^ (r & 7)) << 3)];
            }
#pragma unroll
            for (int m = 0; m < 4; ++m)
#pragma unroll
                for (int n = 0; n < 4; ++n)
                    acc[m][n] = __builtin_amdgcn_mfma_f32_16x16x32_f16(
                        af[m], bfv[n], acc[m][n], 0, 0, 0);
        }
        __syncthreads();
    }

    // epilogue: C/D layout col = lane&15, row = (lane>>4)*4 + reg
    const int cr = (lane >> 4) * 4;
    const int cc = lane & 15;
    if (MODE == 0) {
#pragma unroll
        for (int m = 0; m < 4; ++m) {
#pragma unroll
            for (int n = 0; n < 4; ++n) {
                const int col = bcol + wc + n * 16 + cc;
                const float bv = bias[col];
                const int row0 = brow + wr + m * 16 + cr;
#pragma unroll
                for (int rg = 0; rg < 4; ++rg)
                    C[(size_t)(row0 + rg) * N + col] = acc[m][n][rg] + bv;
            }
        }
    } else {
        const int colbase = bcol + wc;            // 64-aligned: one (matrix, head)
        const int sel = colbase >> 10;            // 0=q 1=k 2=v
        const int hh = (colbase & 1023) >> 6;
#pragma unroll
        for (int m = 0; m < 4; ++m) {
            const int row0 = brow + wr + m * 16 + cr;
            const int bidx = row0 >> 11, t0 = row0 & (L_ - 1);
            if (sel == 2) { // v -> transposed fp16
#pragma unroll
                for (int n = 0; n < 4; ++n) {
                    int col = colbase + n * 16 + cc;
                    float bv = bias[col];
                    int d = col & 63;
                    ushort4 pk = make_ushort4(
                        f2h(acc[m][n][0] + bv), f2h(acc[m][n][1] + bv),
                        f2h(acc[m][n][2] + bv), f2h(acc[m][n][3] + bv));
                    *(ushort4*)&vtb[((((size_t)bidx * NH_ + hh) * HD_) + d) * L_ + t0] = pk;
                }
            } else {        // q or k -> fused RoPE, fp16
                u16* dst = (sel == 0) ? qb : kb;
#pragma unroll
                for (int np = 0; np < 2; ++np) {
                    int col1 = colbase + np * 16 + cc;
                    int d1 = np * 16 + cc;        // [0,32)
                    float bv1 = bias[col1], bv2 = bias[col1 + 32];
#pragma unroll
                    for (int rg = 0; rg < 4; ++rg) {
                        int t = t0 + rg;
                        float c = ctab[((size_t)bidx * L_ + t) * 32 + d1];
                        float s = stab[((size_t)bidx * L_ + t) * 32 + d1];
                        float x1 = acc[m][np][rg] + bv1;
                        float x2 = acc[m][np + 2][rg] + bv2;
                        size_t base = ((((size_t)bidx * NH_ + hh) * L_) + t) * (size_t)HD_;
                        dst[base + d1]      = f2h(x1 * c - x2 * s);
                        dst[base + d1 + 32] = f2h(x2 * c + x1 * s);
                    }
                }
            }
        }
    }
}

// ---------------------------------------------------------------------------
// Kernel 4: segment-masked flash attention (r11-exact restore — best known).
// 8 waves x 16 q-rows (QBLK=128); swapped-operand QK^T (mfma(K,Q));
// no-max log2-domain softmax with interior-tile fast path; P via
// wave-private LDS (pkrtz packs, no barrier); PV swapped -> O^T;
// double-buffered K/V with prefetch-before-compute; setprio around MFMA.
// ---------------------------------------------------------------------------
__global__ __launch_bounds__(512)
void attn_mfma(const u16* __restrict__ qb, const u16* __restrict__ kbuf,
               const u16* __restrict__ vt, const int* __restrict__ sstart,
               const int* __restrict__ send, u16* __restrict__ ohi)
{
    __shared__ u16 Ksb[2][64 * 64];
    __shared__ u16 Vsb[2][64 * 64];
    __shared__ u16 Pw[8][16 * 64]; // per-wave P, [q][key] slot-swizzled
    __shared__ int ss[QBLK], se[QBLK];

    const int b = blockIdx.z, h = blockIdx.y, q0 = blockIdx.x * QBLK;
    const int tid = threadIdx.x, wave = tid >> 6, lane = tid & 63;
    const int fr = lane & 15, kg = lane >> 4;
    const size_t hb = (((size_t)b * NH_) + h) * (size_t)(L_ * HD_); // qb,kb
    const size_t hv = (((size_t)b * NH_) + h) * (size_t)(HD_ * L_); // vt

    if (tid < QBLK) { ss[tid] = sstart[b * L_ + q0 + tid]; se[tid] = send[b * L_ + q0 + tid]; }

    const u16* qrow = &qb[hb + (size_t)(q0 + wave * 16 + fr) * HD_ + kg * 8];
    half8 qf0 = *(const half8*)(qrow);
    half8 qf1 = *(const half8*)(qrow + 32);
    __syncthreads();

    int kmin = 0x7fffffff, kmax = 0;
#pragma unroll 8
    for (int r = 0; r < QBLK; ++r) { kmin = min(kmin, ss[r]); kmax = max(kmax, se[r]); }

    const int myss_ = ss[wave * 16 + fr];   // per-lane: one q-row
    const int myse_ = se[wave * 16 + fr];

    float l_ = 0.f;
    f32x4 oacc[4];
#pragma unroll
    for (int i = 0; i < 4; ++i) oacc[i] = (f32x4){0.f, 0.f, 0.f, 0.f};

    // staging: 512 threads x 16B = one full 64x64 fp16 tile per gload16 round
    const int grow = tid >> 3;             // LDS row 0..63
    const int sg = (tid & 7) ^ (grow & 7); // pre-swizzled source slot
    const float SCL = 0.015625f * 1.4426950408889634f; // (1/64)*log2(e)
    const int fx = fr & 7;
    u16* pwl = &Pw[wave][fr * 64];

    const int kt_first = kmin & ~63;
    if (kt_first < kmax) {
        gload16(&kbuf[hb + (size_t)(kt_first + grow) * HD_ + sg * 8],
                (char*)Ksb[0] + wave * 1024);
        gload16(&vt[hv + (size_t)grow * L_ + kt_first + sg * 8],
                (char*)Vsb[0] + wave * 1024);
    }
    __syncthreads();

    int bufi = 0;
    for (int kt0 = kt_first; kt0 < kmax; kt0 += 64) {
        // prefetch next tile into the other buffer
        if (kt0 + 64 < kmax) {
            gload16(&kbuf[hb + (size_t)(kt0 + 64 + grow) * HD_ + sg * 8],
                    (char*)Ksb[bufi ^ 1] + wave * 1024);
            gload16(&vt[hv + (size_t)grow * L_ + kt0 + 64 + sg * 8],
                    (char*)Vsb[bufi ^ 1] + wave * 1024);
        }
        const u16* Ks = Ksb[bufi];
        const u16* Vs = Vsb[bufi];

        // swapped QK^T: sc4[ct] = S^T[key = kt0+ct*16+kg*4+reg][q = w*16+fr]
        f32x4 sc4[4];
#pragma unroll
        for (int ct = 0; ct < 4; ++ct) sc4[ct] = (f32x4){0.f, 0.f, 0.f, 0.f};
        __builtin_amdgcn_s_setprio(1);
#pragma unroll
        for (int kk = 0; kk < 2; ++kk) {
            half8 qf = kk ? qf1 : qf0;
#pragma unroll
            for (int ct = 0; ct < 4; ++ct) {
                int r = ct * 16 + fr;
                half8 kf = *(const half8*)&Ks[r * 64 + (((kk * 4 + kg) ^ (r & 7)) << 3)];
                sc4[ct] = __builtin_amdgcn_mfma_f32_16x16x32_f16(kf, qf, sc4[ct], 0, 0, 0);
            }
        }
        __builtin_amdgcn_s_setprio(0);

        // probs: no max-subtraction (shift-invariant; scores tiny)
        float p[4][4];
        float psum = 0.f;
        if (__all((kt0 >= myss_) && (kt0 + 64 <= myse_))) {
            // interior tile: no masking at all
#pragma unroll
            for (int ct = 0; ct < 4; ++ct)
#pragma unroll
                for (int reg = 0; reg < 4; ++reg) {
                    float e = fexp2(sc4[ct][reg] * SCL);
                    p[ct][reg] = e;
                    psum += e;
                }
        } else {
            const int ktb = kt0 + kg * 4;
#pragma unroll
            for (int ct = 0; ct < 4; ++ct)
#pragma unroll
                for (int reg = 0; reg < 4; ++reg) {
                    int kt = ktb + ct * 16 + reg;
                    bool v = (kt >= myss_) && (kt < myse_);
                    float e = fexp2(sc4[ct][reg] * SCL);
                    p[ct][reg] = v ? e : 0.f;
                    psum += p[ct][reg];
                }
        }
        psum += __shfl_xor(psum, 16);
        psum += __shfl_xor(psum, 32);
        l_ += psum;

        // pack P -> wave-private LDS (same-wave producer/consumer: no barrier)
#pragma unroll
        for (int ct = 0; ct < 4; ++ct) {
            uint2 w;
            w.x = pkrtz(p[ct][0], p[ct][1]);
            w.y = pkrtz(p[ct][2], p[ct][3]);
            *(uint2*)&pwl[(((2 * ct + (kg >> 1)) ^ fx) << 3) + (kg & 1) * 4] = w;
        }

        // PV swapped: oacc[dt] = mfma(Vt_tile, P) -> O^T[d][q]
        __builtin_amdgcn_s_setprio(1);
#pragma unroll
        for (int ks2 = 0; ks2 < 2; ++ks2) {
            half8 pf = *(const half8*)&pwl[((4 * ks2 + kg) ^ fx) << 3];
#pragma unroll
            for (int dt = 0; dt < 4; ++dt) {
                int r = dt * 16 + fr;
                half8 vf = *(const half8*)&Vs[r * 64 + (((ks2 * 4 + kg) ^ (r & 7)) << 3)];
                oacc[dt] = __builtin_amdgcn_mfma_f32_16x16x32_f16(vf, pf, oacc[dt], 0, 0, 0);
            }
        }
        __builtin_amdgcn_s_setprio(0);
        __syncthreads(); // drains prefetch + all waves done with bufi
        bufi ^= 1;
    }

    // epilogue: q = q0+wave*16+fr; d = dt*16 + kg*4 + reg (reg-consecutive)
    const int t = q0 + wave * 16 + fr;
    const float inv = (myss_ < myse_) ? 1.f / l_ : 0.f;
    const size_t rowbase = ((size_t)b * L_ + t) * (size_t)HID_ + h * HD_ + kg * 4;
#pragma unroll
    for (int dt = 0; dt < 4; ++dt) {
        *(ushort4*)&ohi[rowbase + dt * 16] = make_ushort4(
            f2h(oacc[dt][0] * inv), f2h(oacc[dt][1] * inv),
            f2h(oacc[dt][2] * inv), f2h(oacc[dt][3] * inv));
    }
}

// ---------------------------------------------------------------------------
extern "C" void kernel_launch(void* const* d_in, const int* in_sizes, int n_in,
                              void* d_out, int out_size, void* d_ws, size_t ws_size,
                              hipStream_t stream)
{
    (void)in_sizes; (void)n_in; (void)out_size; (void)ws_size;
    const float* hidden = (const float*)d_in[0];
    const int*   aml    = (const int*)d_in[1];
    const float* Wqkv   = (const float*)d_in[2];
    const float* bqkv   = (const float*)d_in[3];
    const float* Wout   = (const float*)d_in[4];
    const float* bout   = (const float*)d_in[5];
    float* out = (float*)d_out;

    const size_t per = (size_t)B_ * NH_ * L_ * HD_; // 4,194,304
    float* ctab = (float*)d_ws;
    float* stab = ctab + (size_t)B_ * L_ * 32;
    int* sstart = (int*)(stab + (size_t)B_ * L_ * 32);
    int* send   = sstart + B_ * L_;
    int* poss   = send + B_ * L_;
    u16* qbf  = (u16*)(poss + B_ * L_);             // fp16 q (post-rope)
    u16* kbf  = qbf + per;                          // fp16 k (post-rope)
    u16* vtb  = kbf + per;                          // fp16 v transposed [B,NH,HD,L]
    u16* hidh = vtb + per;                          // fp16 A plane (hidden, then attn-out)
    u16* wqh  = hidh + (size_t)4096 * 1024;         // WqkvT fp16 [3072][1024]
    u16* woh  = wqh + (size_t)3072 * 1024;          // WoutT fp16 [1024][1024]

    conv_all<<<dim3(8194), dim3(256), 0, stream>>>(hidden, hidh, Wqkv, wqh,
                                                   Wout, woh, aml, sstart, send, poss);

    trig_kernel<<<dim3((B_ * L_ * 32) / 256), dim3(256), 0, stream>>>(poss, ctab, stab);

    gemm_mfma<1><<<dim3(24, 32), dim3(256), 0, stream>>>(
        hidh, wqh, bqkv, nullptr, qbf, kbf, vtb, ctab, stab,
        B_ * L_, 3 * HID_, HID_);

    attn_mfma<<<dim3(L_ / QBLK, NH_, B_), dim3(512), 0, stream>>>(
        qbf, kbf, vtb, sstart, send, hidh);

    gemm_mfma<0><<<dim3(8, 32), dim3(256), 0, stream>>>(
        hidh, woh, bout, out, nullptr, nullptr, nullptr, nullptr, nullptr,
        B_ * L_, HID_, HID_);
}

// Round 17
// 104.404 us; speedup vs baseline: 1.0879x; 1.0139x over previous
//
#include <hip/hip_runtime.h>
#include <math.h>

#define B_ 2
#define L_ 2048
#define HID_ 1024
#define NH_ 16
#define HD_ 64
#define QBLK 128

typedef unsigned short u16;
typedef __attribute__((ext_vector_type(8))) _Float16 half8; // 8 fp16 = 4 VGPR
typedef __attribute__((ext_vector_type(4))) float f32x4;

__device__ __forceinline__ u16 f2h(float x) { // RNE fp32 -> fp16 bits
    _Float16 h = (_Float16)x; u16 r; __builtin_memcpy(&r, &h, 2); return r;
}
__device__ __forceinline__ float fexp2(float x) { // v_exp_f32, 1 inst
    float r;
    asm("v_exp_f32 %0, %1" : "=v"(r) : "v"(x));
    return r;
}
__device__ __forceinline__ float ffract(float x) {
    float r;
    asm("v_fract_f32 %0, %1" : "=v"(r) : "v"(x));
    return r;
}
__device__ __forceinline__ float fsin_rev(float x) { // sin(2*pi*x), x in [0,1)
    float r;
    asm("v_sin_f32 %0, %1" : "=v"(r) : "v"(x));
    return r;
}
__device__ __forceinline__ float fcos_rev(float x) { // cos(2*pi*x), x in [0,1)
    float r;
    asm("v_cos_f32 %0, %1" : "=v"(r) : "v"(x));
    return r;
}
__device__ __forceinline__ unsigned pkrtz(float a, float b) { // 2xf32 -> packed fp16x2
    auto v = __builtin_amdgcn_cvt_pkrtz(a, b); // __fp16 ext_vector(2)
    unsigned r; __builtin_memcpy(&r, &v, 4); return r;
}
__device__ __forceinline__ void gload16(const void* g, void* l) {
    __builtin_amdgcn_global_load_lds(
        (const __attribute__((address_space(1))) void*)g,
        (__attribute__((address_space(3))) void*)l, 16, 0, 0);
}

// ---------------------------------------------------------------------------
// Kernel 1: merged conversions + segment bookkeeping (one launch):
//  blocks [0,4096)        : hidden fp32 -> fp16 plane (row-linear)
//  blocks [4096,7168)     : Wqkv  [1024][3072] -> WqkvT fp16 [3072][1024]
//  blocks [7168,8192)     : Wout  [1024][1024] -> WoutT fp16 [1024][1024]
//  blocks [8192,8194)     : per-batch segment bookkeeping (prefix sum etc.)
// ---------------------------------------------------------------------------
__global__ void conv_all(const float* __restrict__ hidden, u16* __restrict__ hidh,
                         const float* __restrict__ Wqkv, u16* __restrict__ wqh,
                         const float* __restrict__ Wout, u16* __restrict__ woh,
                         const int* __restrict__ aml,
                         int* __restrict__ sstart, int* __restrict__ send,
                         int* __restrict__ poss_out)
{
    __shared__ float t[32][33];
    const int bid = blockIdx.x;
    const int tid = threadIdx.x;
    if (bid < 4096) {
        int i = (bid * 256 + tid) * 4;
        float4 v = *(const float4*)&hidden[i];
        *(ushort4*)&hidh[i] = make_ushort4(f2h(v.x), f2h(v.y), f2h(v.z), f2h(v.w));
        return;
    }
    if (bid >= 8192) { // segment bookkeeping, b = bid - 8192
        const int b = bid - 8192;
        __shared__ int cs[L_];
        __shared__ int partial[256];
        int vals[8];
        const int t0 = tid * 8;
        int s = 0;
#pragma unroll
        for (int e = 0; e < 8; ++e) { vals[e] = aml[b * L_ + t0 + e]; s += vals[e]; }
        partial[tid] = s;
        __syncthreads();
        if (tid == 0) {
            int acc = 0;
            for (int i = 0; i < 256; ++i) { int tmp = partial[i]; partial[i] = acc; acc += tmp; }
        }
        __syncthreads();
        int off = partial[tid];
#pragma unroll
        for (int e = 0; e < 8; ++e) { off += vals[e]; cs[t0 + e] = off; }
        __syncthreads();
        const int total = cs[L_ - 1];
        for (int tt = tid; tt < L_; tt += 256) {
            int lo = 0, hi = L_;
            while (lo < hi) { int mid = (lo + hi) >> 1; if (cs[mid] <= tt) lo = mid + 1; else hi = mid; }
            int seg = lo < (L_ - 1) ? lo : (L_ - 1);
            int end = cs[seg];
            int len = aml[b * L_ + seg];
            int start = end - len;
            bool valid = tt < total;
            poss_out[b * L_ + tt] = valid ? (tt - start) : 0;
            sstart[b * L_ + tt] = valid ? start : 0x7fffffff;
            send[b * L_ + tt]   = valid ? end : 0;
        }
        return;
    }
    const float* W; u16* o; int Kd = 1024, Nd, n0, k0;
    if (bid < 7168) {
        int idx = bid - 4096; W = Wqkv; o = wqh; Nd = 3072;
        n0 = (idx % 96) * 32; k0 = (idx / 96) * 32;
    } else {
        int idx = bid - 7168; W = Wout; o = woh; Nd = 1024;
        n0 = (idx & 31) * 32; k0 = (idx >> 5) * 32;
    }
    const int r = tid >> 5, c = tid & 31;
#pragma unroll
    for (int i = 0; i < 4; ++i)
        t[r + 8 * i][c] = W[(size_t)(k0 + r + 8 * i) * Nd + n0 + c];
    __syncthreads();
#pragma unroll
    for (int i = 0; i < 4; ++i)
        o[(size_t)(n0 + r + 8 * i) * Kd + k0 + c] = f2h(t[c][r + 8 * i]);
}

// ---------------------------------------------------------------------------
// Kernel 2/4: single-plane fp16 MFMA GEMM (m97 structure, verified).
// MODE 0: C fp32 row-major + bias.
// MODE 1: fused RoPE on q,k -> fp16 [B,NH,L,HD] with ON-THE-FLY trig
//         (v_exp2 inv_freq + v_fract range-reduce + v_sin/v_cos, revolution
//         domain; phase err <= ~8e-5 rad, far under the bf16 output floor);
//         v -> fp16 transposed vt [B,NH,HD,L].
// ---------------------------------------------------------------------------
template <int MODE>
__global__ __launch_bounds__(256, 3)
void gemm_mfma(const u16* __restrict__ Ap, const u16* __restrict__ Bp,
               const float* __restrict__ bias, float* __restrict__ C,
               u16* __restrict__ qb, u16* __restrict__ kb, u16* __restrict__ vtb,
               const int* __restrict__ poss,
               int M, int N, int K)
{
    __shared__ u16 Asl[128 * 64]; // A tile
    __shared__ u16 Bsl[128 * 64]; // B tile

    const int tid = threadIdx.x;
    const int wave = tid >> 6, lane = tid & 63;

    const int nwg = gridDim.x * gridDim.y;
    const int bid = blockIdx.y * gridDim.x + blockIdx.x;
    const int cpx = nwg >> 3;
    const int swz = (bid & 7) * cpx + (bid >> 3);
    const int brow = (swz / gridDim.x) * 128;
    const int bcol = (swz % gridDim.x) * 128;

    const int wr = (wave >> 1) * 64, wc = (wave & 1) * 64;
    const int grow = tid >> 3, gslot = tid & 7;
    const int fr = lane & 15, kg = lane >> 4;

    f32x4 acc[4][4];
#pragma unroll
    for (int m = 0; m < 4; ++m)
#pragma unroll
        for (int n = 0; n < 4; ++n) acc[m][n] = (f32x4){0.f, 0.f, 0.f, 0.f};

    for (int ka = 0; ka < K; ka += 64) {
#pragma unroll
        for (int c = 0; c < 4; ++c) {
            int row = c * 32 + grow;
            int sg = gslot ^ (row & 7);
            gload16(&Ap[(size_t)(brow + row) * K + ka + sg * 8],
                    (char*)Asl + c * 4096 + wave * 1024);
            gload16(&Bp[(size_t)(bcol + row) * K + ka + sg * 8],
                    (char*)Bsl + c * 4096 + wave * 1024);
        }
        __syncthreads();

#pragma unroll
        for (int kk = 0; kk < 2; ++kk) {
            half8 af[4], bfv[4];
            const int cbase = kk * 4 + kg;
#pragma unroll
            for (int n = 0; n < 4; ++n) {
                int r = wc + n * 16 + fr;
                bfv[n] = *(const half8*)&Bsl[r * 64 + ((cbase ^ (r & 7)) << 3)];
            }
#pragma unroll
            for (int m = 0; m < 4; ++m) {
                int r = wr + m * 16 + fr;
                af[m] = *(const half8*)&Asl[r * 64 + ((cbase ^ (r & 7)) << 3)];
            }
#pragma unroll
            for (int m = 0; m < 4; ++m)
#pragma unroll
                for (int n = 0; n < 4; ++n)
                    acc[m][n] = __builtin_amdgcn_mfma_f32_16x16x32_f16(
                        af[m], bfv[n], acc[m][n], 0, 0, 0);
        }
        __syncthreads();
    }

    // epilogue: C/D layout col = lane&15, row = (lane>>4)*4 + reg
    const int cr = (lane >> 4) * 4;
    const int cc = lane & 15;
    if (MODE == 0) {
#pragma unroll
        for (int m = 0; m < 4; ++m) {
#pragma unroll
            for (int n = 0; n < 4; ++n) {
                const int col = bcol + wc + n * 16 + cc;
                const float bv = bias[col];
                const int row0 = brow + wr + m * 16 + cr;
#pragma unroll
                for (int rg = 0; rg < 4; ++rg)
                    C[(size_t)(row0 + rg) * N + col] = acc[m][n][rg] + bv;
            }
        }
    } else {
        const int colbase = bcol + wc;            // 64-aligned: one (matrix, head)
        const int sel = colbase >> 10;            // 0=q 1=k 2=v
        const int hh = (colbase & 1023) >> 6;
        if (sel == 2) { // v -> transposed fp16
#pragma unroll
            for (int m = 0; m < 4; ++m) {
                const int row0 = brow + wr + m * 16 + cr;
                const int bidx = row0 >> 11, t0 = row0 & (L_ - 1);
#pragma unroll
                for (int n = 0; n < 4; ++n) {
                    int col = colbase + n * 16 + cc;
                    float bv = bias[col];
                    int d = col & 63;
                    ushort4 pk = make_ushort4(
                        f2h(acc[m][n][0] + bv), f2h(acc[m][n][1] + bv),
                        f2h(acc[m][n][2] + bv), f2h(acc[m][n][3] + bv));
                    *(ushort4*)&vtb[((((size_t)bidx * NH_ + hh) * HD_) + d) * L_ + t0] = pk;
                }
            }
        } else {        // q or k -> fused RoPE (on-the-fly trig), fp16
            u16* dst = (sel == 0) ? qb : kb;
            // per-thread constants: d1 = np*16 + cc, np in {0,1}
            const float NEGK = -0.41524101186092574f;  // -log2(10000)/32
            const float I2PI = 0.15915494309189535f;   // 1/(2*pi)
            const float rf0 = fexp2((float)cc * NEGK) * I2PI;        // np=0
            const float rf1 = fexp2((float)(16 + cc) * NEGK) * I2PI; // np=1
            const float bv10 = bias[colbase + cc];
            const float bv20 = bias[colbase + cc + 32];
            const float bv11 = bias[colbase + 16 + cc];
            const float bv21 = bias[colbase + 16 + cc + 32];
#pragma unroll
            for (int m = 0; m < 4; ++m) {
                const int row0 = brow + wr + m * 16 + cr;
                const int bidx = row0 >> 11, t0 = row0 & (L_ - 1);
#pragma unroll
                for (int rg = 0; rg < 4; ++rg) {
                    int t = t0 + rg;
                    float ps = (float)poss[bidx * L_ + t];
                    size_t base = ((((size_t)bidx * NH_ + hh) * L_) + t) * (size_t)HD_;
                    // np = 0: d1 = cc
                    {
                        float fr_ = ffract(ps * rf0);
                        float c = fcos_rev(fr_), s = fsin_rev(fr_);
                        float x1 = acc[m][0][rg] + bv10;
                        float x2 = acc[m][2][rg] + bv20;
                        dst[base + cc]      = f2h(x1 * c - x2 * s);
                        dst[base + cc + 32] = f2h(x2 * c + x1 * s);
                    }
                    // np = 1: d1 = 16 + cc
                    {
                        float fr_ = ffract(ps * rf1);
                        float c = fcos_rev(fr_), s = fsin_rev(fr_);
                        float x1 = acc[m][1][rg] + bv11;
                        float x2 = acc[m][3][rg] + bv21;
                        dst[base + 16 + cc]      = f2h(x1 * c - x2 * s);
                        dst[base + 16 + cc + 32] = f2h(x2 * c + x1 * s);
                    }
                }
            }
        }
    }
}

// ---------------------------------------------------------------------------
// Kernel 3: segment-masked flash attention (r11 structure — best known).
// 8 waves x 16 q-rows (QBLK=128); swapped-operand QK^T (mfma(K,Q));
// no-max log2-domain softmax with interior-tile fast path; P via
// wave-private LDS (pkrtz packs, no barrier); PV swapped -> O^T;
// double-buffered K/V with prefetch-before-compute; setprio around MFMA.
// ---------------------------------------------------------------------------
__global__ __launch_bounds__(512)
void attn_mfma(const u16* __restrict__ qb, const u16* __restrict__ kbuf,
               const u16* __restrict__ vt, const int* __restrict__ sstart,
               const int* __restrict__ send, u16* __restrict__ ohi)
{
    __shared__ u16 Ksb[2][64 * 64];
    __shared__ u16 Vsb[2][64 * 64];
    __shared__ u16 Pw[8][16 * 64]; // per-wave P, [q][key] slot-swizzled
    __shared__ int ss[QBLK], se[QBLK];

    const int b = blockIdx.z, h = blockIdx.y, q0 = blockIdx.x * QBLK;
    const int tid = threadIdx.x, wave = tid >> 6, lane = tid & 63;
    const int fr = lane & 15, kg = lane >> 4;
    const size_t hb = (((size_t)b * NH_) + h) * (size_t)(L_ * HD_); // qb,kb
    const size_t hv = (((size_t)b * NH_) + h) * (size_t)(HD_ * L_); // vt

    if (tid < QBLK) { ss[tid] = sstart[b * L_ + q0 + tid]; se[tid] = send[b * L_ + q0 + tid]; }

    const u16* qrow = &qb[hb + (size_t)(q0 + wave * 16 + fr) * HD_ + kg * 8];
    half8 qf0 = *(const half8*)(qrow);
    half8 qf1 = *(const half8*)(qrow + 32);
    __syncthreads();

    int kmin = 0x7fffffff, kmax = 0;
#pragma unroll 8
    for (int r = 0; r < QBLK; ++r) { kmin = min(kmin, ss[r]); kmax = max(kmax, se[r]); }

    const int myss_ = ss[wave * 16 + fr];   // per-lane: one q-row
    const int myse_ = se[wave * 16 + fr];

    float l_ = 0.f;
    f32x4 oacc[4];
#pragma unroll
    for (int i = 0; i < 4; ++i) oacc[i] = (f32x4){0.f, 0.f, 0.f, 0.f};

    // staging: 512 threads x 16B = one full 64x64 fp16 tile per gload16 round
    const int grow = tid >> 3;             // LDS row 0..63
    const int sg = (tid & 7) ^ (grow & 7); // pre-swizzled source slot
    const float SCL = 0.015625f * 1.4426950408889634f; // (1/64)*log2(e)
    const int fx = fr & 7;
    u16* pwl = &Pw[wave][fr * 64];

    const int kt_first = kmin & ~63;
    if (kt_first < kmax) {
        gload16(&kbuf[hb + (size_t)(kt_first + grow) * HD_ + sg * 8],
                (char*)Ksb[0] + wave * 1024);
        gload16(&vt[hv + (size_t)grow * L_ + kt_first + sg * 8],
                (char*)Vsb[0] + wave * 1024);
    }
    __syncthreads();

    int bufi = 0;
    for (int kt0 = kt_first; kt0 < kmax; kt0 += 64) {
        // prefetch next tile into the other buffer
        if (kt0 + 64 < kmax) {
            gload16(&kbuf[hb + (size_t)(kt0 + 64 + grow) * HD_ + sg * 8],
                    (char*)Ksb[bufi ^ 1] + wave * 1024);
            gload16(&vt[hv + (size_t)grow * L_ + kt0 + 64 + sg * 8],
                    (char*)Vsb[bufi ^ 1] + wave * 1024);
        }
        const u16* Ks = Ksb[bufi];
        const u16* Vs = Vsb[bufi];

        // swapped QK^T: sc4[ct] = S^T[key = kt0+ct*16+kg*4+reg][q = w*16+fr]
        f32x4 sc4[4];
#pragma unroll
        for (int ct = 0; ct < 4; ++ct) sc4[ct] = (f32x4){0.f, 0.f, 0.f, 0.f};
        __builtin_amdgcn_s_setprio(1);
#pragma unroll
        for (int kk = 0; kk < 2; ++kk) {
            half8 qf = kk ? qf1 : qf0;
#pragma unroll
            for (int ct = 0; ct < 4; ++ct) {
                int r = ct * 16 + fr;
                half8 kf = *(const half8*)&Ks[r * 64 + (((kk * 4 + kg) ^ (r & 7)) << 3)];
                sc4[ct] = __builtin_amdgcn_mfma_f32_16x16x32_f16(kf, qf, sc4[ct], 0, 0, 0);
            }
        }
        __builtin_amdgcn_s_setprio(0);

        // probs: no max-subtraction (shift-invariant; scores tiny)
        float p[4][4];
        float psum = 0.f;
        if (__all((kt0 >= myss_) && (kt0 + 64 <= myse_))) {
            // interior tile: no masking at all
#pragma unroll
            for (int ct = 0; ct < 4; ++ct)
#pragma unroll
                for (int reg = 0; reg < 4; ++reg) {
                    float e = fexp2(sc4[ct][reg] * SCL);
                    p[ct][reg] = e;
                    psum += e;
                }
        } else {
            const int ktb = kt0 + kg * 4;
#pragma unroll
            for (int ct = 0; ct < 4; ++ct)
#pragma unroll
                for (int reg = 0; reg < 4; ++reg) {
                    int kt = ktb + ct * 16 + reg;
                    bool v = (kt >= myss_) && (kt < myse_);
                    float e = fexp2(sc4[ct][reg] * SCL);
                    p[ct][reg] = v ? e : 0.f;
                    psum += p[ct][reg];
                }
        }
        psum += __shfl_xor(psum, 16);
        psum += __shfl_xor(psum, 32);
        l_ += psum;

        // pack P -> wave-private LDS (same-wave producer/consumer: no barrier)
#pragma unroll
        for (int ct = 0; ct < 4; ++ct) {
            uint2 w;
            w.x = pkrtz(p[ct][0], p[ct][1]);
            w.y = pkrtz(p[ct][2], p[ct][3]);
            *(uint2*)&pwl[(((2 * ct + (kg >> 1)) ^ fx) << 3) + (kg & 1) * 4] = w;
        }

        // PV swapped: oacc[dt] = mfma(Vt_tile, P) -> O^T[d][q]
        __builtin_amdgcn_s_setprio(1);
#pragma unroll
        for (int ks2 = 0; ks2 < 2; ++ks2) {
            half8 pf = *(const half8*)&pwl[((4 * ks2 + kg) ^ fx) << 3];
#pragma unroll
            for (int dt = 0; dt < 4; ++dt) {
                int r = dt * 16 + fr;
                half8 vf = *(const half8*)&Vs[r * 64 + (((ks2 * 4 + kg) ^ (r & 7)) << 3)];
                oacc[dt] = __builtin_amdgcn_mfma_f32_16x16x32_f16(vf, pf, oacc[dt], 0, 0, 0);
            }
        }
        __builtin_amdgcn_s_setprio(0);
        __syncthreads(); // drains prefetch + all waves done with bufi
        bufi ^= 1;
    }

    // epilogue: q = q0+wave*16+fr; d = dt*16 + kg*4 + reg (reg-consecutive)
    const int t = q0 + wave * 16 + fr;
    const float inv = (myss_ < myse_) ? 1.f / l_ : 0.f;
    const size_t rowbase = ((size_t)b * L_ + t) * (size_t)HID_ + h * HD_ + kg * 4;
#pragma unroll
    for (int dt = 0; dt < 4; ++dt) {
        *(ushort4*)&ohi[rowbase + dt * 16] = make_ushort4(
            f2h(oacc[dt][0] * inv), f2h(oacc[dt][1] * inv),
            f2h(oacc[dt][2] * inv), f2h(oacc[dt][3] * inv));
    }
}

// ---------------------------------------------------------------------------
extern "C" void kernel_launch(void* const* d_in, const int* in_sizes, int n_in,
                              void* d_out, int out_size, void* d_ws, size_t ws_size,
                              hipStream_t stream)
{
    (void)in_sizes; (void)n_in; (void)out_size; (void)ws_size;
    const float* hidden = (const float*)d_in[0];
    const int*   aml    = (const int*)d_in[1];
    const float* Wqkv   = (const float*)d_in[2];
    const float* bqkv   = (const float*)d_in[3];
    const float* Wout   = (const float*)d_in[4];
    const float* bout   = (const float*)d_in[5];
    float* out = (float*)d_out;

    const size_t per = (size_t)B_ * NH_ * L_ * HD_; // 4,194,304
    int* sstart = (int*)d_ws;
    int* send   = sstart + B_ * L_;
    int* poss   = send + B_ * L_;
    u16* qbf  = (u16*)(poss + B_ * L_);             // fp16 q (post-rope)
    u16* kbf  = qbf + per;                          // fp16 k (post-rope)
    u16* vtb  = kbf + per;                          // fp16 v transposed [B,NH,HD,L]
    u16* hidh = vtb + per;                          // fp16 A plane (hidden, then attn-out)
    u16* wqh  = hidh + (size_t)4096 * 1024;         // WqkvT fp16 [3072][1024]
    u16* woh  = wqh + (size_t)3072 * 1024;          // WoutT fp16 [1024][1024]

    conv_all<<<dim3(8194), dim3(256), 0, stream>>>(hidden, hidh, Wqkv, wqh,
                                                   Wout, woh, aml, sstart, send, poss);

    gemm_mfma<1><<<dim3(24, 32), dim3(256), 0, stream>>>(
        hidh, wqh, bqkv, nullptr, qbf, kbf, vtb, poss,
        B_ * L_, 3 * HID_, HID_);

    attn_mfma<<<dim3(L_ / QBLK, NH_, B_), dim3(512), 0, stream>>>(
        qbf, kbf, vtb, sstart, send, hidh);

    gemm_mfma<0><<<dim3(8, 32), dim3(256), 0, stream>>>(
        hidh, woh, bout, out, nullptr, nullptr, nullptr, nullptr,
        B_ * L_, HID_, HID_);
}